// Round 1
// baseline (51.432 us; speedup 1.0000x reference)
//
#include <hip/hip_runtime.h>
#include <hip/hip_bf16.h>
#include <math.h>

// CWT Morlet via bf16 MFMA GEMM, round 14.
// r13 + pack_weights ELIMINATED: A fragments are loaded directly from the
// f32 weight buffers and converted in-register with v_cvt_pk_bf16_f32 (same
// RNE rounding as __float2bfloat16 -> bit-identical taps). Removes one
// serial dependent dispatch (~2.5-4us: 104-block latency-bound kernel +
// graph-node gap).
// Correctness: only group 0's last kstep (kc23, taps 736..767) crosses the
// KW=763 boundary. g0's ks=24 main loop is shortened to 5 iterations and a
// hand-written 4-kstep tail loads kc23 via ld8w_tail (zeroes taps >= 763:
// oct==3, elems j>=3). All other in-range and dead prefetch loads stay
// within each group's rows (checked per group: max dead tap 735 for g1,
// <=575 elsewhere; g0 dead prefetch kc24 reads rows 0..15 neighbors,
// in-buffer, never consumed).

#define T_LEN 16384
#define KW    763
#define HALF  381
#define NSC   128
#define NFR   256
#define TPB   256
#define TBLK  128
#define NSLOT 119           // 16B chunks per copy
#define WLEN  (8 * NSLOT)   // 952 staged f32 window
#define CP_SH (NSLOT * 8)   // shorts per copy (1904 B stride)

typedef __attribute__((ext_vector_type(8))) short short8;
typedef __attribute__((ext_vector_type(4))) float f32x4;

union S8U { short8 s; unsigned u[4]; };

static __device__ inline unsigned cvt_pk_bf16(float lo, float hi) {
    unsigned r;
    asm volatile("v_cvt_pk_bf16_f32 %0, %1, %2" : "=v"(r) : "v"(lo), "v"(hi));
    return r;
}

// load 8 consecutive f32 taps, convert to packed bf16 fragment
static __device__ inline short8 ld8w(const float* p) {
    float f[8];
    __builtin_memcpy(f, p, 32);
    S8U pk;
    pk.u[0] = cvt_pk_bf16(f[0], f[1]);
    pk.u[1] = cvt_pk_bf16(f[2], f[3]);
    pk.u[2] = cvt_pk_bf16(f[4], f[5]);
    pk.u[3] = cvt_pk_bf16(f[6], f[7]);
    return pk.s;
}

// tail variant for g0/kc23: oct 3 spans taps 760..767; taps 763..767 are
// beyond the filter (they alias the next scale row) -> zero elems j>=3.
static __device__ inline short8 ld8w_tail(const float* p, int oct) {
    float f[8];
    __builtin_memcpy(f, p, 32);
    if (oct == 3) { f[3] = 0.f; f[4] = 0.f; f[5] = 0.f; f[6] = 0.f; f[7] = 0.f; }
    S8U pk;
    pk.u[0] = cvt_pk_bf16(f[0], f[1]);
    pk.u[1] = cvt_pk_bf16(f[2], f[3]);
    pk.u[2] = cvt_pk_bf16(f[4], f[5]);
    pk.u[3] = cvt_pk_bf16(f[6], f[7]);
    return pk.s;
}

#define MFMA16(A, B, C) __builtin_amdgcn_mfma_f32_16x16x32_bf16(A, B, C, 0, 0, 0)

__global__ __launch_bounds__(TPB, 3) void cwt_mfma_kernel(
    const float* __restrict__ x,
    const float* __restrict__ wr,
    const float* __restrict__ wi,
    float* __restrict__ out)
{
    __shared__ __align__(16) float xw[WLEN];
    __shared__ __align__(16) short cps[8 * CP_SH];

    const int tid  = threadIdx.x;
    const int lane = tid & 63;
    const int ws   = tid >> 6;        // wave 0..3
    const int n    = lane & 15;       // col (t within 16) / A row
    const int oct  = lane >> 4;       // k-octet 0..3
    const int blk  = blockIdx.x;      // t-block 0..127
    const int sg   = blockIdx.y;      // signal 0..11
    const int t0   = blk * TBLK;
    const int wse  = (ws + blk) & 3;  // rotated group-set -> SIMD balance

    // ---- stage f32 window (reflected) ----
    const float* xsig = x + sg * T_LEN;
    for (int u = tid; u < WLEN; u += TPB) {
        int gg = t0 - HALF + u;
        if (gg < 0) gg = -gg;
        if (gg >= T_LEN) gg = 2 * T_LEN - 2 - gg;
        xw[u] = xsig[gg];
    }
    __syncthreads();

    // ---- 8 shifted bf16 copies: copy c chunk m = xw[8m+c .. +7]; permuted
    // lane->(c,m) so concurrent b128 writes hit distinct bank-quads ----
    for (int u = tid; u < 8 * NSLOT; u += TPB) {
        const int m = u >> 3;
        const int c = (u + m) & 7;
        const int base = 8 * m + c;
        S8U pk;
        pk.u[0] = cvt_pk_bf16(xw[base],     xw[base + 1]);
        pk.u[1] = cvt_pk_bf16(xw[base + 2], xw[base + 3]);
        pk.u[2] = cvt_pk_bf16(xw[base + 4], xw[base + 5]);
        pk.u[3] = cvt_pk_bf16(xw[base + 6], xw[base + 7]);
        *(short8*)&cps[c * CP_SH + m * 8] = pk.s;
    }
    __syncthreads();

    const float lg20  = 1.301029995663981f;
    const float stepl = (2.653212513775344f - 1.301029995663981f) / 127.0f;

    // group-sets: 0 -> {0}, 1 -> {1,7}, 2 -> {2,3}, 3 -> {4,5,6}
    const int ng   = (wse == 0) ? 1 : (wse == 3) ? 3 : 2;
    const int gseq = (wse == 0) ? 0x0 : (wse == 1) ? 0x71 :
                     (wse == 2) ? 0x32 : 0x654;

    for (int gi = 0; gi < ng; ++gi) {
        const int g  = (gseq >> (4 * gi)) & 15;
        const int s0 = 16 * g;
        float fg = exp10f(lg20 + (float)s0 * stepl);
        int hg = (int)(7639.43726841098f / fg) + 2;
        if (hg > HALF) hg = HALF;
        const int k0 = (HALF - hg) & ~31;
        const int ks = (HALF + hg + 1 - k0 + 31) >> 5;   // even for all groups

        f32x4 acR0, acI0, acR1, acI1, acR2, acI2, acR3, acI3;
        f32x4 acR4, acI4, acR5, acI5, acR6, acI6, acR7, acI7;
        acR0 = acI0 = acR1 = acI1 = (f32x4){0.f, 0.f, 0.f, 0.f};
        acR2 = acI2 = acR3 = acI3 = (f32x4){0.f, 0.f, 0.f, 0.f};
        acR4 = acI4 = acR5 = acI5 = (f32x4){0.f, 0.f, 0.f, 0.f};
        acR6 = acI6 = acR7 = acI7 = (f32x4){0.f, 0.f, 0.f, 0.f};

        // A: direct f32 loads + in-register bf16 cvt, 4-pair ring,
        // 2-deep prefetch (offsets in floats: 32 per kstep)
        const float* pR = wr + (size_t)(s0 + n) * KW + k0 + oct * 8;
        const float* pI = wi + (size_t)(s0 + n) * KW + k0 + oct * 8;
        short8 aAr = ld8w(pR),      aAi = ld8w(pI);
        short8 aBr = ld8w(pR + 32), aBi = ld8w(pI + 32);
        short8 aCr, aCi, aDr, aDi;

        // B: 8-slot ring over even chunks m0 + {0,2,...,14} (+4/kstep)
        const int s_i0 = n + 8 * oct + k0;
        const char* bp = (const char*)cps
                       + (s_i0 & 7) * (2 * CP_SH)
                       + ((s_i0 >> 3) << 4);
        short8 b0 = *(const short8*)(bp);
        short8 b1 = *(const short8*)(bp + 32);
        short8 b2 = *(const short8*)(bp + 64);
        short8 b3 = *(const short8*)(bp + 96);
        short8 b4 = *(const short8*)(bp + 128);
        short8 b5 = *(const short8*)(bp + 160);
        short8 b6 = *(const short8*)(bp + 192);
        short8 b7 = *(const short8*)(bp + 224);

#define KSTEP(AR, AI, PR_, PI_, PFO, S0_,S1_,S2_,S3_,S4_,S5_,S6_,S7_, R0, R1) \
        {                                                                     \
            __builtin_amdgcn_s_setprio(1);                                    \
            acR0 = MFMA16(AR, S0_, acR0);  acI0 = MFMA16(AI, S0_, acI0);      \
            acR1 = MFMA16(AR, S1_, acR1);  acI1 = MFMA16(AI, S1_, acI1);      \
            S0_ = *(const short8*)(bp + (R0));                                \
            S1_ = *(const short8*)(bp + (R1));                                \
            PR_ = ld8w(pR + (PFO));  PI_ = ld8w(pI + (PFO));                  \
            acR2 = MFMA16(AR, S2_, acR2);  acI2 = MFMA16(AI, S2_, acI2);      \
            acR3 = MFMA16(AR, S3_, acR3);  acI3 = MFMA16(AI, S3_, acI3);      \
            acR4 = MFMA16(AR, S4_, acR4);  acI4 = MFMA16(AI, S4_, acI4);      \
            acR5 = MFMA16(AR, S5_, acR5);  acI5 = MFMA16(AI, S5_, acI5);      \
            acR6 = MFMA16(AR, S6_, acR6);  acI6 = MFMA16(AI, S6_, acI6);      \
            acR7 = MFMA16(AR, S7_, acR7);  acI7 = MFMA16(AI, S7_, acI7);      \
            __builtin_amdgcn_s_setprio(0);                                    \
        }

#define KSTEP_NR(AR, AI, S0_,S1_,S2_,S3_,S4_,S5_,S6_,S7_)                     \
        {                                                                     \
            __builtin_amdgcn_s_setprio(1);                                    \
            acR0 = MFMA16(AR, S0_, acR0);  acI0 = MFMA16(AI, S0_, acI0);      \
            acR1 = MFMA16(AR, S1_, acR1);  acI1 = MFMA16(AI, S1_, acI1);      \
            acR2 = MFMA16(AR, S2_, acR2);  acI2 = MFMA16(AI, S2_, acI2);      \
            acR3 = MFMA16(AR, S3_, acR3);  acI3 = MFMA16(AI, S3_, acI3);      \
            acR4 = MFMA16(AR, S4_, acR4);  acI4 = MFMA16(AI, S4_, acI4);      \
            acR5 = MFMA16(AR, S5_, acR5);  acI5 = MFMA16(AI, S5_, acI5);      \
            acR6 = MFMA16(AR, S6_, acR6);  acI6 = MFMA16(AI, S6_, acI6);      \
            acR7 = MFMA16(AR, S7_, acR7);  acI7 = MFMA16(AI, S7_, acI7);      \
            __builtin_amdgcn_s_setprio(0);                                    \
        }

        // g0 (ks==24): run 5 main iterations (kc0..19), then explicit 4-tail
        // so kc23's A fragment can be boundary-masked. Others: full main
        // loop + existing 2-tail.
        const int itEnd = (g == 0) ? 20 : ks;

        for (int it = 0; it + 4 <= itEnd; it += 4) {
            KSTEP(aAr, aAi, aCr, aCi, 64,
                  b0, b1, b2, b3, b4, b5, b6, b7, 256, 288)
            KSTEP(aBr, aBi, aDr, aDi, 96,
                  b2, b3, b4, b5, b6, b7, b0, b1, 320, 352)
            KSTEP(aCr, aCi, aAr, aAi, 128,
                  b4, b5, b6, b7, b0, b1, b2, b3, 384, 416)
            KSTEP(aDr, aDi, aBr, aBi, 160,
                  b6, b7, b0, b1, b2, b3, b4, b5, 448, 480)
            pR += 128;  pI += 128;
            bp += 256;
        }
        if (g == 0) {
            // tail: consume kc20..kc23 (ring state: aA=kc20, aB=kc21).
            // T1: consume kc20, prefetch kc22 -> aC (taps <=735, valid).
            KSTEP(aAr, aAi, aCr, aCi, 64,
                  b0, b1, b2, b3, b4, b5, b6, b7, 256, 288)
            // T2: consume kc21, prefetch kc23 -> aD with boundary mask.
            {
                __builtin_amdgcn_s_setprio(1);
                acR0 = MFMA16(aBr, b2, acR0);  acI0 = MFMA16(aBi, b2, acI0);
                acR1 = MFMA16(aBr, b3, acR1);  acI1 = MFMA16(aBi, b3, acI1);
                b2 = *(const short8*)(bp + 320);
                b3 = *(const short8*)(bp + 352);
                aDr = ld8w_tail(pR + 96, oct);  aDi = ld8w_tail(pI + 96, oct);
                acR2 = MFMA16(aBr, b4, acR2);  acI2 = MFMA16(aBi, b4, acI2);
                acR3 = MFMA16(aBr, b5, acR3);  acI3 = MFMA16(aBi, b5, acI3);
                acR4 = MFMA16(aBr, b6, acR4);  acI4 = MFMA16(aBi, b6, acI4);
                acR5 = MFMA16(aBr, b7, acR5);  acI5 = MFMA16(aBi, b7, acI5);
                acR6 = MFMA16(aBr, b0, acR6);  acI6 = MFMA16(aBi, b0, acI6);
                acR7 = MFMA16(aBr, b1, acR7);  acI7 = MFMA16(aBi, b1, acI7);
                __builtin_amdgcn_s_setprio(0);
            }
            // T3: consume kc22; prefetch (kc24) is dead but in-buffer
            // (rows 0..15, flat idx <= 15*763+799 << KW*NSC).
            KSTEP(aCr, aCi, aAr, aAi, 128,
                  b4, b5, b6, b7, b0, b1, b2, b3, 384, 416)
            // T4: consume kc23 (masked fragment), no refill.
            KSTEP_NR(aDr, aDi, b6, b7, b0, b1, b2, b3, b4, b5)
        } else if (ks & 2) {
            // tail kstep 1: full KSTEP -> refills b0,b1 (chunks m0+16,18);
            // its A prefetch is dead but in-row (max dead tap 735 @ g1).
            KSTEP(aAr, aAi, aCr, aCi, 64,
                  b0, b1, b2, b3, b4, b5, b6, b7, 256, 288)
            // tail kstep 2: consumes b2..b7 and the FRESH b0,b1.
            KSTEP_NR(aBr, aBi, b2, b3, b4, b5, b6, b7, b0, b1)
        }
#undef KSTEP
#undef KSTEP_NR

        // ---- epilogue: mag + log1p, pack-tree 16-lane pool, 2 frames ----
        const float C = 0.6931471805599453f / 64.0f;
        #pragma unroll
        for (int f = 0; f < 2; ++f) {
            float v[4];
            #pragma unroll
            for (int r = 0; r < 4; ++r) {
                float s;
                if (f == 0) {
                    float m0 = fmaf(acR0[r], acR0[r], fmaf(acI0[r], acI0[r], 1e-8f));
                    float m1 = fmaf(acR1[r], acR1[r], fmaf(acI1[r], acI1[r], 1e-8f));
                    float m2 = fmaf(acR2[r], acR2[r], fmaf(acI2[r], acI2[r], 1e-8f));
                    float m3 = fmaf(acR3[r], acR3[r], fmaf(acI3[r], acI3[r], 1e-8f));
                    s = __builtin_amdgcn_logf(1.f + __builtin_amdgcn_sqrtf(m0))
                      + __builtin_amdgcn_logf(1.f + __builtin_amdgcn_sqrtf(m1))
                      + __builtin_amdgcn_logf(1.f + __builtin_amdgcn_sqrtf(m2))
                      + __builtin_amdgcn_logf(1.f + __builtin_amdgcn_sqrtf(m3));
                } else {
                    float m0 = fmaf(acR4[r], acR4[r], fmaf(acI4[r], acI4[r], 1e-8f));
                    float m1 = fmaf(acR5[r], acR5[r], fmaf(acI5[r], acI5[r], 1e-8f));
                    float m2 = fmaf(acR6[r], acR6[r], fmaf(acI6[r], acI6[r], 1e-8f));
                    float m3 = fmaf(acR7[r], acR7[r], fmaf(acI7[r], acI7[r], 1e-8f));
                    s = __builtin_amdgcn_logf(1.f + __builtin_amdgcn_sqrtf(m0))
                      + __builtin_amdgcn_logf(1.f + __builtin_amdgcn_sqrtf(m1))
                      + __builtin_amdgcn_logf(1.f + __builtin_amdgcn_sqrtf(m2))
                      + __builtin_amdgcn_logf(1.f + __builtin_amdgcn_sqrtf(m3));
                }
                v[r] = s;
            }
            #pragma unroll
            for (int r = 0; r < 4; ++r) v[r] += __shfl_xor(v[r], 1);
            float w0 = (lane & 1) ? v[1] : v[0];
            float w1 = (lane & 1) ? v[3] : v[2];
            w0 += __shfl_xor(w0, 2);
            w1 += __shfl_xor(w1, 2);
            float u = (lane & 2) ? w1 : w0;
            u += __shfl_xor(u, 4);
            u += __shfl_xor(u, 8);
            if (n < 4) {
                const int srow  = s0 + 4 * oct + (n & 3);
                const int frame = blk * 2 + f;
                out[(sg * NSC + srow) * NFR + frame] = u * C;
            }
        }
    }
}

extern "C" void kernel_launch(void* const* d_in, const int* in_sizes, int n_in,
                              void* d_out, int out_size, void* d_ws, size_t ws_size,
                              hipStream_t stream) {
    (void)in_sizes; (void)n_in; (void)out_size; (void)d_ws; (void)ws_size;
    const float* x  = (const float*)d_in[0];
    const float* wr = (const float*)d_in[1];
    const float* wi = (const float*)d_in[2];
    float* out = (float*)d_out;

    dim3 grid(T_LEN / TBLK, 12);
    cwt_mfma_kernel<<<grid, TPB, 0, stream>>>(x, wr, wi, out);
}